// Round 4
// baseline (506.332 us; speedup 1.0000x reference)
//
#include <hip/hip_runtime.h>

typedef float f32x4 __attribute__((ext_vector_type(4)));
typedef short bf16x8 __attribute__((ext_vector_type(8)));

__device__ __forceinline__ unsigned short f2bf(float f){
    unsigned int u = __builtin_bit_cast(unsigned int, f);
    u = u + 0x7fffu + ((u >> 16) & 1u);   // RNE
    return (unsigned short)(u >> 16);
}
__device__ __forceinline__ float bf2f(unsigned short h){
    unsigned int u = ((unsigned int)h) << 16;
    return __builtin_bit_cast(float, u);
}
// RTZ pack: 1-2 VALU instead of ~9; threshold headroom covers the extra ulp
__device__ __forceinline__ unsigned int pk2_rtz(float a, float b){
    unsigned int ua = __builtin_bit_cast(unsigned int, a);
    unsigned int ub = __builtin_bit_cast(unsigned int, b);
    return (ua >> 16) | (ub & 0xffff0000u);
}
__device__ __forceinline__ unsigned short bfrtz(float a){
    return (unsigned short)(__builtin_bit_cast(unsigned int, a) >> 16);
}
// gelu(tanh approx) == x * sigmoid(1.5957691*(x + 0.044715 x^3))  (exact identity)
__device__ __forceinline__ float gelu_f(float x){
    float t = x * x;
    float u = fmaf(0.044715f, t, 1.0f);
    float y = 1.5957691216057308f * x * u;
    float e = __expf(-y);
    return x * __builtin_amdgcn_rcpf(1.0f + e);
}

// B-fragment pack position for mfma_f32_16x16x32_bf16:
// lane l needs B[k = kt*32 + (l>>4)*8 + j][n = nt*16 + (l&15)], j=0..7 contiguous.
__device__ __forceinline__ int packpos(int k, int n, int NT){
    int kt = k >> 5, quad = (k >> 3) & 3, j = k & 7;
    int nt = n >> 4, nl = n & 15;
    return ((kt * NT + nt) * 64 + quad * 16 + nl) * 8 + j;
}

// ---- prep: all weight packing in one kernel (grid = 323) ----
// bid 0..63   : Bp1 = bf16(scale[k] * W_h1[k][n])
// bid 64      : BpL = W_logit padded to 16 cols
// bid 65      : b_combo = b_h + b_ego@W_h2 + ln_bias@W_h1   (broadcasts via LDS)
// bid 66      : v1 = colsum of bf16-rounded scale*W_h1      (broadcasts via LDS)
// bid 67..322 : Bpc = W_ego @ W_h2 row (bid-67), packed bf16
__global__ __launch_bounds__(256) void prep(const float* __restrict__ Wh,
        const float* __restrict__ Wlogit, const float* __restrict__ Wego,
        const float* __restrict__ b_ego, const float* __restrict__ b_h,
        const float* __restrict__ ln_s, const float* __restrict__ ln_b,
        unsigned short* __restrict__ Bp1, unsigned short* __restrict__ BpL,
        unsigned short* __restrict__ Bpc, float* __restrict__ b_combo,
        float* __restrict__ v1){
    __shared__ float rowbuf[512];
    int bid = blockIdx.x, tid = threadIdx.x;
    if (bid < 64){
        int base = (bid * 256 + tid) * 4;
        int k = base >> 8;
        float sc = ln_s[k];
        for (int e = base; e < base + 4; ++e){
            int n = e & 255;
            Bp1[packpos(k, n, 16)] = f2bf(sc * Wh[k * 256 + n]);
        }
    } else if (bid == 64){
        for (int e = tid * 16; e < tid * 16 + 16; ++e){
            int k = e >> 4, n = e & 15;
            float v = (n < 4) ? Wlogit[k * 4 + n] : 0.0f;
            BpL[packpos(k, n, 1)] = f2bf(v);
        }
    } else if (bid == 65){
        rowbuf[tid]       = b_ego[tid];
        rowbuf[256 + tid] = ln_b[tid];
        __syncthreads();
        float acc = b_h[tid];
        for (int j = 0; j < 256; ++j) acc += rowbuf[j] * Wh[(256 + j) * 256 + tid];
        for (int k = 0; k < 256; ++k) acc += rowbuf[256 + k] * Wh[k * 256 + tid];
        b_combo[tid] = acc;
    } else if (bid == 66){
        rowbuf[tid] = ln_s[tid];
        __syncthreads();
        float acc = 0.f;
        for (int k = 0; k < 256; ++k)
            acc += bf2f(f2bf(rowbuf[k] * Wh[k * 256 + tid]));
        v1[tid] = acc;
    } else {
        int k = bid - 67;
        rowbuf[tid] = Wego[k * 256 + tid];
        __syncthreads();
        float acc = 0.f;
        const float4* row4 = (const float4*)rowbuf;
        for (int j4 = 0; j4 < 64; ++j4){
            float4 e = row4[j4];
            int j = j4 * 4;
            acc += e.x * Wh[(256 + j) * 256 + tid];
            acc += e.y * Wh[(257 + j) * 256 + tid];
            acc += e.z * Wh[(258 + j) * 256 + tid];
            acc += e.w * Wh[(259 + j) * 256 + tid];
        }
        Bpc[packpos(k, tid, 16)] = f2bf(acc);
    }
}

// ---- ego_gemm: ego_term[8192][256] = bf16(ego_ctx @ W_combo + b_combo) ----
__global__ __launch_bounds__(256) void ego_gemm(const float* __restrict__ ego_ctx,
        const unsigned short* __restrict__ Bpc, const float* __restrict__ b_combo,
        unsigned short* __restrict__ ego_term){
    const int tid = threadIdx.x, w = tid >> 6, l = tid & 63;
    const int m0 = blockIdx.x * 16;
    const int row = m0 + (l & 15);
    const int kq = (l >> 4) << 3;
    f32x4 acc[4];
    #pragma unroll
    for (int j = 0; j < 4; ++j) acc[j] = 0;
    #pragma unroll
    for (int kt = 0; kt < 8; ++kt){
        const float* ap = ego_ctx + row * 256 + kt * 32 + kq;
        float4 x0 = *(const float4*)ap;
        float4 x1 = *(const float4*)(ap + 4);
        unsigned int ua[4];
        ua[0] = ((unsigned int)f2bf(x0.x)) | ((unsigned int)f2bf(x0.y) << 16);
        ua[1] = ((unsigned int)f2bf(x0.z)) | ((unsigned int)f2bf(x0.w) << 16);
        ua[2] = ((unsigned int)f2bf(x1.x)) | ((unsigned int)f2bf(x1.y) << 16);
        ua[3] = ((unsigned int)f2bf(x1.z)) | ((unsigned int)f2bf(x1.w) << 16);
        bf16x8 a = __builtin_bit_cast(bf16x8, *(uint4*)ua);
        #pragma unroll
        for (int j = 0; j < 4; ++j){
            int nt = w * 4 + j;
            bf16x8 b = *(const bf16x8*)&Bpc[((kt * 16 + nt) * 64 + l) * 8];
            acc[j] = __builtin_amdgcn_mfma_f32_16x16x32_bf16(a, b, acc[j], 0, 0, 0);
        }
    }
    const int rq = (l >> 4) << 2, colc = l & 15;
    #pragma unroll
    for (int j = 0; j < 4; ++j){
        int n = (w * 4 + j) * 16 + colc;
        float bc = b_combo[n];
        #pragma unroll
        for (int rg = 0; rg < 4; ++rg)
            ego_term[(m0 + rq + rg) * 256 + n] = f2bf(acc[j][rg] + bc);
    }
}

// ---- main: m-partitioned, ONE barrier.
// Wave w owns rows [16w,16w+16): stages them, GEMMs them against all 256 cols
// (B streamed from L2/L1), stats+epilogue+logits all wave-local; single
// __syncthreads before the cross-wave softmax; readout fused in-wave via shfl.
__global__ __launch_bounds__(256) void main_fused(const float* __restrict__ inv,
        const float* __restrict__ rin, const float* __restrict__ uin,
        const int* __restrict__ mask, const float* __restrict__ b_logit,
        const unsigned short* __restrict__ Bp1, const unsigned short* __restrict__ BpL,
        const unsigned short* __restrict__ ego_term, const float* __restrict__ v1g,
        float* __restrict__ out){

    __shared__ unsigned short Albs[64 * 264];   // X then h (bf16), stride 264
    __shared__ float2 stats_s[64];              // {rstd, rstd*mean}
    __shared__ float logit_s[256];

    const int tid = threadIdx.x;
    const int w = tid >> 6, l = tid & 63;
    const int T0 = blockIdx.x * 64;
    const int bn0 = blockIdx.x * 2;
    const int col = l & 15, quad = l >> 4, kq = quad << 3;
    const int r0 = w * 16;
    const int gw = w >> 1;                      // this wave's (b,n) group

    // --- prefetch softmax/readout operands (consumed after the barrier) ---
    const int h_sm = ((w & 1) << 1) + (l >> 5);
    const int k_sm = l & 31;
    const int row_sm = gw * 32 + k_sm;
    const int mvalid = mask[T0 + row_sm];
    const float blg = b_logit[h_sm];
    const float* rp = rin + (T0 + row_sm) * 3;
    const float* up = uin + (T0 + row_sm) * 3;
    float rv0 = rp[0], rv1 = rp[1], rv2 = rp[2];
    float uv0 = up[0], uv1 = up[1], uv2 = up[2];

    // --- stage own 16 rows as bf16 (wave-local: no barrier needed) ---
    {
        const float* base = inv + (T0 + r0) * 256 + l * 4;
        #pragma unroll
        for (int rr = 0; rr < 16; ++rr){
            float4 c = *(const float4*)(base + rr * 256);
            uint2 p;
            p.x = pk2_rtz(c.x, c.y);
            p.y = pk2_rtz(c.z, c.w);
            *(uint2*)&Albs[(r0 + rr) * 264 + l * 4] = p;
        }
    }

    // --- GEMM: rows [r0,r0+16) x all 256 cols; stats ride the MFMA pipe ---
    f32x4 acc[16];
    #pragma unroll
    for (int i = 0; i < 16; ++i) acc[i] = 0;
    f32x4 gacc = 0, sacc = 0;
    bf16x8 ones;
    #pragma unroll
    for (int j = 0; j < 8; ++j) ones[j] = (short)0x3F80;

    #pragma unroll
    for (int kt = 0; kt < 8; ++kt){
        bf16x8 af = *(const bf16x8*)&Albs[(r0 + col) * 264 + kt * 32 + kq];
        gacc = __builtin_amdgcn_mfma_f32_16x16x32_bf16(af, af,   gacc, 0, 0, 0);
        sacc = __builtin_amdgcn_mfma_f32_16x16x32_bf16(af, ones, sacc, 0, 0, 0);
        #pragma unroll
        for (int nt = 0; nt < 16; ++nt){
            bf16x8 bv = *(const bf16x8*)&Bp1[((kt * 16 + nt) * 64 + l) * 8];
            acc[nt] = __builtin_amdgcn_mfma_f32_16x16x32_bf16(af, bv, acc[nt], 0, 0, 0);
        }
    }

    // --- stats finalize (wave-local LDS; lockstep + lgkmcnt, no barrier) ---
    if ((col >> 2) == quad){
        int rg = col & 3;
        float mean = sacc[rg] * (1.0f / 256.0f);
        float var  = gacc[rg] * (1.0f / 256.0f) - mean * mean;
        float rstd = rsqrtf(var + 1e-6f);
        stats_s[r0 + col] = float2{rstd, rstd * mean};
    }
    float2 st[4];
    #pragma unroll
    for (int rg = 0; rg < 4; ++rg) st[rg] = stats_s[r0 + quad * 4 + rg];

    // --- epilogue: h = gelu(rstd*Craw - (rstd*mean)*v1 + ego) -> own Albs rows ---
    #pragma unroll
    for (int nt = 0; nt < 16; ++nt){
        const int n = nt * 16 + col;
        const float v1n = v1g[n];
        const float egn = bf2f(ego_term[(bn0 + gw) * 256 + n]);
        #pragma unroll
        for (int rg = 0; rg < 4; ++rg){
            float x = fmaf(st[rg].x, acc[nt][rg], fmaf(-st[rg].y, v1n, egn));
            Albs[(r0 + quad * 4 + rg) * 264 + n] = bfrtz(gelu_f(x));
        }
    }

    // --- logits = h @ W_logit (own rows, wave-local) ---
    {
        f32x4 lacc = 0;
        #pragma unroll
        for (int kt = 0; kt < 8; ++kt){
            bf16x8 a = *(const bf16x8*)&Albs[(r0 + col) * 264 + kt * 32 + kq];
            bf16x8 b = *(const bf16x8*)&BpL[(kt * 64 + l) * 8];
            lacc = __builtin_amdgcn_mfma_f32_16x16x32_bf16(a, b, lacc, 0, 0, 0);
        }
        if (col < 4){
            #pragma unroll
            for (int rg = 0; rg < 4; ++rg)
                logit_s[(r0 + quad * 4 + rg) * 4 + col] = lacc[rg];
        }
    }

    __syncthreads();   // the ONE barrier: logits cross waves into softmax

    // --- masked softmax (32 lanes per (group, head)) + fused readout ---
    {
        float lg = logit_s[row_sm * 4 + h_sm] + blg;
        float val = mvalid ? lg : -3.0e38f;
        float mx = val;
        #pragma unroll
        for (int off = 16; off >= 1; off >>= 1)
            mx = fmaxf(mx, __shfl_xor(mx, off));
        float e = mvalid ? __expf(lg - mx) : 0.0f;
        float ssum = e;
        #pragma unroll
        for (int off = 16; off >= 1; off >>= 1)
            ssum += __shfl_xor(ssum, off);
        float a = (ssum > 0.f) ? e / ssum : 0.0f;
        out[196608 + (T0 + row_sm) * 4 + h_sm] = a;

        float p0 = a * rv0, p1 = a * rv1, p2 = a * rv2;
        float p3 = a * uv0, p4 = a * uv1, p5 = a * uv2;
        #pragma unroll
        for (int off = 16; off >= 1; off >>= 1){
            p0 += __shfl_xor(p0, off);
            p1 += __shfl_xor(p1, off);
            p2 += __shfl_xor(p2, off);
            p3 += __shfl_xor(p3, off);
            p4 += __shfl_xor(p4, off);
            p5 += __shfl_xor(p5, off);
        }
        if (k_sm == 0){
            int ob = (bn0 + gw) * 12 + h_sm * 3;
            out[ob    ] = p0;
            out[ob + 1] = p1;
            out[ob + 2] = p2;
            out[98304 + ob    ] = p3;
            out[98304 + ob + 1] = p4;
            out[98304 + ob + 2] = p5;
        }
    }
}

extern "C" void kernel_launch(void* const* d_in, const int* in_sizes, int n_in,
                              void* d_out, int out_size, void* d_ws, size_t ws_size,
                              hipStream_t stream){
    const float* inv    = (const float*)d_in[0];
    const float* ego    = (const float*)d_in[1];
    const float* rin    = (const float*)d_in[2];
    const float* uin    = (const float*)d_in[3];
    const int*   mask   = (const int*)  d_in[4];
    const float* Wego   = (const float*)d_in[5];
    const float* b_ego  = (const float*)d_in[6];
    const float* ln_s   = (const float*)d_in[7];
    const float* ln_b   = (const float*)d_in[8];
    const float* Wh     = (const float*)d_in[9];
    const float* b_h    = (const float*)d_in[10];
    const float* Wlogit = (const float*)d_in[11];
    const float* b_lg   = (const float*)d_in[12];
    float* out = (float*)d_out;

    unsigned short* wsu = (unsigned short*)d_ws;
    unsigned short* Bp1 = wsu;                       // 65536 bf16
    unsigned short* Bpc = wsu + 65536;               // 65536 bf16
    unsigned short* BpL = wsu + 131072;              // 4096 bf16
    float* b_combo      = (float*)(wsu + 135168);    // 256 f32
    float* v1           = (float*)(wsu + 135680);    // 256 f32
    unsigned short* ego_term = wsu + 136192;         // 8192*256 bf16

    prep<<<323, 256, 0, stream>>>(Wh, Wlogit, Wego, b_ego, b_h, ln_s, ln_b,
                                  Bp1, BpL, Bpc, b_combo, v1);
    ego_gemm<<<512, 256, 0, stream>>>(ego, Bpc, b_combo, ego_term);
    main_fused<<<4096, 256, 0, stream>>>(inv, rin, uin, mask, b_lg,
                                         Bp1, BpL, ego_term, v1, out);
}

// Round 5
// 460.395 us; speedup vs baseline: 1.0998x; 1.0998x over previous
//
#include <hip/hip_runtime.h>

typedef float f32x4 __attribute__((ext_vector_type(4)));
typedef short bf16x8 __attribute__((ext_vector_type(8)));

__device__ __forceinline__ unsigned short f2bf(float f){
    unsigned int u = __builtin_bit_cast(unsigned int, f);
    u = u + 0x7fffu + ((u >> 16) & 1u);   // RNE
    return (unsigned short)(u >> 16);
}
__device__ __forceinline__ float bf2f(unsigned short h){
    unsigned int u = ((unsigned int)h) << 16;
    return __builtin_bit_cast(float, u);
}
// RTZ pack for activations (1-2 VALU); RNE f2bf kept for weights
__device__ __forceinline__ unsigned int pk2_rtz(float a, float b){
    unsigned int ua = __builtin_bit_cast(unsigned int, a);
    unsigned int ub = __builtin_bit_cast(unsigned int, b);
    return (ua >> 16) | (ub & 0xffff0000u);
}
__device__ __forceinline__ unsigned short bfrtz(float a){
    return (unsigned short)(__builtin_bit_cast(unsigned int, a) >> 16);
}
// gelu(tanh approx) == x * sigmoid(1.5957691*(x + 0.044715 x^3))  (exact identity)
__device__ __forceinline__ float gelu_f(float x){
    float t = x * x;
    float u = fmaf(0.044715f, t, 1.0f);
    float y = 1.5957691216057308f * x * u;
    float e = __expf(-y);
    return x * __builtin_amdgcn_rcpf(1.0f + e);
}

// B-fragment pack position for mfma_f32_16x16x32_bf16:
// lane l needs B[k = kt*32 + (l>>4)*8 + j][n = nt*16 + (l&15)], j=0..7 contiguous.
__device__ __forceinline__ int packpos(int k, int n, int NT){
    int kt = k >> 5, quad = (k >> 3) & 3, j = k & 7;
    int nt = n >> 4, nl = n & 15;
    return ((kt * NT + nt) * 64 + quad * 16 + nl) * 8 + j;
}

// ---- K1: Bpc = pack(W_ego @ W_h2)  [bid 0..255],  b_combo [bid 256] ----
__global__ __launch_bounds__(256) void combo_pack(const float* __restrict__ Wh,
        const float* __restrict__ Wego, const float* __restrict__ b_ego,
        const float* __restrict__ b_h, const float* __restrict__ ln_b,
        unsigned short* __restrict__ Bpc, float* __restrict__ b_combo){
    __shared__ float rowbuf[512];
    int bid = blockIdx.x, tid = threadIdx.x;
    if (bid < 256){
        int k = bid;
        rowbuf[tid] = Wego[k * 256 + tid];
        __syncthreads();
        float acc = 0.f;
        const float4* row4 = (const float4*)rowbuf;
        for (int j4 = 0; j4 < 64; ++j4){
            float4 e = row4[j4];
            int j = j4 * 4;
            acc += e.x * Wh[(256 + j) * 256 + tid];
            acc += e.y * Wh[(257 + j) * 256 + tid];
            acc += e.z * Wh[(258 + j) * 256 + tid];
            acc += e.w * Wh[(259 + j) * 256 + tid];
        }
        Bpc[packpos(k, tid, 16)] = f2bf(acc);
    } else {
        rowbuf[tid]       = b_ego[tid];
        rowbuf[256 + tid] = ln_b[tid];
        __syncthreads();
        float acc = b_h[tid];
        for (int j = 0; j < 256; ++j) acc += rowbuf[j] * Wh[(256 + j) * 256 + tid];
        for (int k = 0; k < 256; ++k) acc += rowbuf[256 + k] * Wh[k * 256 + tid];
        b_combo[tid] = acc;
    }
}

// ---- K2: ego_term GEMM [bid 0..511] + Bp1 pack [512..575] + BpL [576] + v1 [577] ----
__global__ __launch_bounds__(256) void ego_plus(const float* __restrict__ ego_ctx,
        const unsigned short* __restrict__ Bpc, const float* __restrict__ b_combo,
        const float* __restrict__ Wh, const float* __restrict__ Wlogit,
        const float* __restrict__ ln_s,
        unsigned short* __restrict__ ego_term, unsigned short* __restrict__ Bp1,
        unsigned short* __restrict__ BpL, float* __restrict__ v1){
    __shared__ float rowbuf[256];
    const int bid = blockIdx.x, tid = threadIdx.x;
    if (bid < 512){
        const int w = tid >> 6, l = tid & 63;
        const int m0 = bid * 16;
        const int row = m0 + (l & 15);
        const int kq = (l >> 4) << 3;
        f32x4 acc[4];
        #pragma unroll
        for (int j = 0; j < 4; ++j) acc[j] = 0;
        #pragma unroll
        for (int kt = 0; kt < 8; ++kt){
            const float* ap = ego_ctx + row * 256 + kt * 32 + kq;
            float4 x0 = *(const float4*)ap;
            float4 x1 = *(const float4*)(ap + 4);
            unsigned int ua[4];
            ua[0] = pk2_rtz(x0.x, x0.y);
            ua[1] = pk2_rtz(x0.z, x0.w);
            ua[2] = pk2_rtz(x1.x, x1.y);
            ua[3] = pk2_rtz(x1.z, x1.w);
            bf16x8 a = __builtin_bit_cast(bf16x8, *(uint4*)ua);
            #pragma unroll
            for (int j = 0; j < 4; ++j){
                int nt = w * 4 + j;
                bf16x8 b = *(const bf16x8*)&Bpc[((kt * 16 + nt) * 64 + l) * 8];
                acc[j] = __builtin_amdgcn_mfma_f32_16x16x32_bf16(a, b, acc[j], 0, 0, 0);
            }
        }
        const int rq = (l >> 4) << 2, colc = l & 15;
        #pragma unroll
        for (int j = 0; j < 4; ++j){
            int n = (w * 4 + j) * 16 + colc;
            float bc = b_combo[n];
            #pragma unroll
            for (int rg = 0; rg < 4; ++rg)
                ego_term[(m0 + rq + rg) * 256 + n] = f2bf(acc[j][rg] + bc);
        }
    } else if (bid < 576){
        int base = ((bid - 512) * 256 + tid) * 4;
        int k = base >> 8;
        float sc = ln_s[k];
        for (int e = base; e < base + 4; ++e){
            int n = e & 255;
            Bp1[packpos(k, n, 16)] = f2bf(sc * Wh[k * 256 + n]);
        }
    } else if (bid == 576){
        for (int e = tid * 16; e < tid * 16 + 16; ++e){
            int k = e >> 4, n = e & 15;
            float v = (n < 4) ? Wlogit[k * 4 + n] : 0.0f;
            BpL[packpos(k, n, 1)] = f2bf(v);
        }
    } else {
        rowbuf[tid] = ln_s[tid];
        __syncthreads();
        float acc = 0.f;
        for (int k = 0; k < 256; ++k)
            acc += bf2f(f2bf(rowbuf[k] * Wh[k * 256 + tid]));
        v1[tid] = acc;
    }
}

// ---- main: 32-row blocks (one (b,n) group), shared-A / wave-partitioned-B.
// Wave w: stages rows [8w,8w+8), GEMMs all 32 rows x n-slice [64w,64w+64),
// stats on MFMA pipe, gelu epilogue -> h in LDS, logits MFMA (waves 0-1),
// in-wave softmax+readout. 4 barriers. ----
__global__ __launch_bounds__(256) void main_fused(const float* __restrict__ inv,
        const float* __restrict__ rin, const float* __restrict__ uin,
        const int* __restrict__ mask, const float* __restrict__ b_logit,
        const unsigned short* __restrict__ Bp1, const unsigned short* __restrict__ BpL,
        const unsigned short* __restrict__ ego_term, const float* __restrict__ v1g,
        float* __restrict__ out){

    __shared__ unsigned short Albs[32 * 264];   // X then h (bf16), stride 264
    __shared__ float2 stats_s[32];              // {rstd, rstd*mean}
    __shared__ float logit_s[128];              // 32 rows x 4 heads

    const int tid = threadIdx.x;
    const int w = tid >> 6, l = tid & 63;
    const int g = blockIdx.x;                   // (b,n) group
    const int T0 = g * 32;                      // flat token row base
    const int col = l & 15, quad = l >> 4, kq = quad << 3;

    // --- prefetch tail operands (waves 0,1 only; consumed after last barrier) ---
    const int h_sm = w * 2 + (l >> 5);
    const int k_sm = l & 31;
    int mvalid = 0; float blg = 0.f;
    float rv0 = 0.f, rv1 = 0.f, rv2 = 0.f, uv0 = 0.f, uv1 = 0.f, uv2 = 0.f;
    if (w < 2){
        mvalid = mask[T0 + k_sm];
        blg = b_logit[h_sm];
        const float* rp = rin + (T0 + k_sm) * 3;
        const float* up = uin + (T0 + k_sm) * 3;
        rv0 = rp[0]; rv1 = rp[1]; rv2 = rp[2];
        uv0 = up[0]; uv1 = up[1]; uv2 = up[2];
    }
    // --- per-lane epilogue constants (L2-resident) ---
    float v1r[4], egn[4];
    #pragma unroll
    for (int i = 0; i < 4; ++i){
        int n = w * 64 + i * 16 + col;
        v1r[i] = v1g[n];
        egn[i] = bf2f(ego_term[g * 256 + n]);
    }

    // --- stage own 8 rows as bf16 ---
    {
        const float* base = inv + (T0 + w * 8) * 256 + l * 4;
        #pragma unroll
        for (int rr = 0; rr < 8; ++rr){
            float4 c = *(const float4*)(base + rr * 256);
            uint2 p;
            p.x = pk2_rtz(c.x, c.y);
            p.y = pk2_rtz(c.z, c.w);
            *(uint2*)&Albs[(w * 8 + rr) * 264 + l * 4] = p;
        }
    }
    __syncthreads();   // B1: X staged

    // --- GEMM: 32 rows x n-slice [64w,64w+64); stats for m-tile (w&1) ride along ---
    f32x4 acc[2][4];
    #pragma unroll
    for (int a = 0; a < 2; ++a)
        #pragma unroll
        for (int b = 0; b < 4; ++b) acc[a][b] = 0;
    f32x4 gacc = 0, sacc = 0;
    bf16x8 ones;
    #pragma unroll
    for (int j = 0; j < 8; ++j) ones[j] = (short)0x3F80;
    const int mts = w & 1;

    #pragma unroll
    for (int kt = 0; kt < 8; ++kt){
        const int ko = kt * 32 + kq;
        bf16x8 af0 = *(const bf16x8*)&Albs[(     col) * 264 + ko];
        bf16x8 af1 = *(const bf16x8*)&Albs[(16 + col) * 264 + ko];
        bf16x8 afs = mts ? af1 : af0;
        gacc = __builtin_amdgcn_mfma_f32_16x16x32_bf16(afs, afs,  gacc, 0, 0, 0);
        sacc = __builtin_amdgcn_mfma_f32_16x16x32_bf16(afs, ones, sacc, 0, 0, 0);
        #pragma unroll
        for (int i = 0; i < 4; ++i){
            bf16x8 bv = *(const bf16x8*)&Bp1[((kt * 16 + (w * 4 + i)) * 64 + l) * 8];
            acc[0][i] = __builtin_amdgcn_mfma_f32_16x16x32_bf16(af0, bv, acc[0][i], 0, 0, 0);
            acc[1][i] = __builtin_amdgcn_mfma_f32_16x16x32_bf16(af1, bv, acc[1][i], 0, 0, 0);
        }
    }
    // --- stats finalize: diag lanes write {rstd, rstd*mean} (dup across w, w+2: identical) ---
    if ((col >> 2) == quad){
        int rg = col & 3;
        float mean = sacc[rg] * (1.0f / 256.0f);
        float var  = gacc[rg] * (1.0f / 256.0f) - mean * mean;
        float rstd = rsqrtf(var + 1e-6f);
        stats_s[mts * 16 + col] = float2{rstd, rstd * mean};
    }
    __syncthreads();   // B2: stats visible + all A reads done

    // --- epilogue: h = gelu(rstd*Craw - (rstd*mean)*v1 + ego) -> Albs (in place) ---
    {
        float2 st[2][4];
        #pragma unroll
        for (int mt = 0; mt < 2; ++mt)
            #pragma unroll
            for (int rg = 0; rg < 4; ++rg)
                st[mt][rg] = stats_s[mt * 16 + quad * 4 + rg];
        #pragma unroll
        for (int mt = 0; mt < 2; ++mt)
            #pragma unroll
            for (int i = 0; i < 4; ++i){
                const int n = w * 64 + i * 16 + col;
                #pragma unroll
                for (int rg = 0; rg < 4; ++rg){
                    float x = fmaf(st[mt][rg].x, acc[mt][i][rg],
                                   fmaf(-st[mt][rg].y, v1r[i], egn[i]));
                    Albs[(mt * 16 + quad * 4 + rg) * 264 + n] = bfrtz(gelu_f(x));
                }
            }
    }
    __syncthreads();   // B3: h complete

    // --- logits = h @ W_logit (waves 0,1: m-tile w) ---
    if (w < 2){
        f32x4 lacc = 0;
        #pragma unroll
        for (int kt = 0; kt < 8; ++kt){
            bf16x8 a = *(const bf16x8*)&Albs[(w * 16 + col) * 264 + kt * 32 + kq];
            bf16x8 b = *(const bf16x8*)&BpL[(kt * 64 + l) * 8];
            lacc = __builtin_amdgcn_mfma_f32_16x16x32_bf16(a, b, lacc, 0, 0, 0);
        }
        if (col < 4){
            #pragma unroll
            for (int rg = 0; rg < 4; ++rg)
                logit_s[(w * 16 + quad * 4 + rg) * 4 + col] = lacc[rg];
        }
    }
    __syncthreads();   // B4: logits visible

    // --- masked softmax (32 lanes per head-pair) + fused readout (waves 0,1) ---
    if (w < 2){
        float lg = logit_s[k_sm * 4 + h_sm] + blg;
        float val = mvalid ? lg : -3.0e38f;
        float mx = val;
        #pragma unroll
        for (int off = 16; off >= 1; off >>= 1)
            mx = fmaxf(mx, __shfl_xor(mx, off));
        float e = mvalid ? __expf(lg - mx) : 0.0f;
        float ssum = e;
        #pragma unroll
        for (int off = 16; off >= 1; off >>= 1)
            ssum += __shfl_xor(ssum, off);
        float a = (ssum > 0.f) ? e / ssum : 0.0f;
        out[196608 + (T0 + k_sm) * 4 + h_sm] = a;

        float p0 = a * rv0, p1 = a * rv1, p2 = a * rv2;
        float p3 = a * uv0, p4 = a * uv1, p5 = a * uv2;
        #pragma unroll
        for (int off = 16; off >= 1; off >>= 1){
            p0 += __shfl_xor(p0, off);
            p1 += __shfl_xor(p1, off);
            p2 += __shfl_xor(p2, off);
            p3 += __shfl_xor(p3, off);
            p4 += __shfl_xor(p4, off);
            p5 += __shfl_xor(p5, off);
        }
        if (k_sm == 0){
            int ob = g * 12 + h_sm * 3;
            out[ob    ] = p0;
            out[ob + 1] = p1;
            out[ob + 2] = p2;
            out[98304 + ob    ] = p3;
            out[98304 + ob + 1] = p4;
            out[98304 + ob + 2] = p5;
        }
    }
}

extern "C" void kernel_launch(void* const* d_in, const int* in_sizes, int n_in,
                              void* d_out, int out_size, void* d_ws, size_t ws_size,
                              hipStream_t stream){
    const float* inv    = (const float*)d_in[0];
    const float* ego    = (const float*)d_in[1];
    const float* rin    = (const float*)d_in[2];
    const float* uin    = (const float*)d_in[3];
    const int*   mask   = (const int*)  d_in[4];
    const float* Wego   = (const float*)d_in[5];
    const float* b_ego  = (const float*)d_in[6];
    const float* ln_s   = (const float*)d_in[7];
    const float* ln_b   = (const float*)d_in[8];
    const float* Wh     = (const float*)d_in[9];
    const float* b_h    = (const float*)d_in[10];
    const float* Wlogit = (const float*)d_in[11];
    const float* b_lg   = (const float*)d_in[12];
    float* out = (float*)d_out;

    unsigned short* wsu = (unsigned short*)d_ws;
    unsigned short* Bp1 = wsu;                       // 65536 bf16
    unsigned short* Bpc = wsu + 65536;               // 65536 bf16
    unsigned short* BpL = wsu + 131072;              // 4096 bf16
    float* b_combo      = (float*)(wsu + 135168);    // 256 f32
    float* v1           = (float*)(wsu + 135680);    // 256 f32
    unsigned short* ego_term = wsu + 136192;         // 8192*256 bf16

    combo_pack<<<257, 256, 0, stream>>>(Wh, Wego, b_ego, b_h, ln_b, Bpc, b_combo);
    ego_plus<<<578, 256, 0, stream>>>(ego, Bpc, b_combo, Wh, Wlogit, ln_s,
                                      ego_term, Bp1, BpL, v1);
    main_fused<<<8192, 256, 0, stream>>>(inv, rin, uin, mask, b_lg,
                                         Bp1, BpL, ego_term, v1, out);
}